// Round 11
// baseline (61.143 us; speedup 1.0000x reference)
//
#include <hip/hip_runtime.h>
#include <hip/hip_bf16.h>

#define S_ 2048
#define E_ 1024
#define QNC 16   // qkv K-chunks of 64 f32

typedef __attribute__((ext_vector_type(8))) short short8;
typedef __attribute__((ext_vector_type(4))) float f32x4;

__device__ __forceinline__ short f2bf(float f) {
    __hip_bfloat16 h = __float2bfloat16(f);
    return *(short*)&h;
}

__device__ __forceinline__ void g2l16(const void* g, void* l) {
    __builtin_amdgcn_global_load_lds(
        (const __attribute__((address_space(1))) void*)g,
        (__attribute__((address_space(3))) void*)l, 16, 0, 0);
}

// Wq/Wk/Wv [1024][64] f32 -> Wtt bf16 in MFMA B-fragment order:
// Wtt[((nt*32 + ks)*64 + lane)*8 + e] = W[k = ks*32 + (lane>>4)*8 + e][col],
// col = nt*16 + (lane&15) over concatenated {Q|K|V} 192 cols.
__global__ __launch_bounds__(256) void prep_weights(
    const float* __restrict__ Wq, const float* __restrict__ Wk,
    const float* __restrict__ Wv, unsigned short* __restrict__ Wtt)
{
    int tw = blockIdx.x * 256 + threadIdx.x;   // 0..24575 (grid 96)
    int nt = tw >> 11;
    int lane = tw & 63;
    int n = nt * 16 + (lane & 15);
    int h = n & 63;
    const float* W = (n < 64) ? Wq : (n < 128) ? Wk : Wv;
    int k0 = ((tw >> 6) & 31) * 32 + (lane >> 4) * 8;
    short8 o;
    #pragma unroll
    for (int e = 0; e < 8; ++e) o[e] = f2bf(W[(k0 + e) * 64 + h]);
    *(short8*)(Wtt + (size_t)tw * 8) = o;
}

// QKV v11: M=16 rows/block, 1024 blocks x 256 thr (4 waves, wave = 16 rows x
// 48 cols), 5-buffer LDS ring (4KB chunks), double-buffered Wtt fragment regs,
// counted vmcnt derived for in-order retirement, coalesced LDS-staged epilogue.
__global__ __launch_bounds__(256, 4) void qkv_main(
    const float* __restrict__ x, const unsigned short* __restrict__ Wtt,
    const float* __restrict__ bq, const float* __restrict__ bk,
    const float* __restrict__ bv,
    unsigned short* __restrict__ Q, unsigned short* __restrict__ K,
    unsigned short* __restrict__ Vt)
{
    __shared__ __align__(16) char lds[5][4096];        // 16 rows x 256B
    __shared__ __align__(16) char eq[16 * 272];        // QK epilogue tile
    __shared__ __align__(16) unsigned short ev[64 * 18]; // V epilogue (36B/h)
    int tid = threadIdx.x;
    int wave = tid >> 6, lane = tid & 63;
    int lo = lane & 15, hi = lane >> 4;
    int wn = wave;                        // col quarter
    int rowbase = blockIdx.x * 16;
    const char* xg = (const char*)x;

    f32x4 acc[3];
    #pragma unroll
    for (int j = 0; j < 3; ++j) acc[j] = (f32x4){0.f, 0.f, 0.f, 0.f};

    // chunk kc: 16 rows x 256B = 256 16B-units, 1 DMA/thread.
    // source pre-swizzled u' = (u&8)|((u&7)^(r&7)); dest linear.
    #define STAGE(bb, kc)                                                         \
        {                                                                         \
            int r_ = tid >> 4, u_ = tid & 15;                                     \
            const char* src = xg + (size_t)(rowbase + r_) * 4096 + (kc) * 256     \
                              + (((u_ & 8) | ((u_ & 7) ^ (r_ & 7))) << 4);        \
            g2l16(src, &lds[bb][wave * 1024]);                                    \
        }

    // B-fragments for chunk t (6 coalesced 16B/lane loads from L2)
    #define LOADB(dst, t)                                                         \
        {                                                                         \
            _Pragma("unroll")                                                     \
            for (int j = 0; j < 3; ++j)                                           \
                _Pragma("unroll")                                                 \
                for (int kk = 0; kk < 2; ++kk)                                    \
                    dst[j][kk] = *(const short8*)(Wtt +                           \
                        (size_t)(((wn * 3 + j) * 32 + (t) * 2 + kk) * 64 + lane) * 8); \
        }

    #define COMPUTE(bfr, t)                                                       \
        {                                                                         \
            const char* lx = lds[(t) % 5];                                        \
            _Pragma("unroll")                                                     \
            for (int kk = 0; kk < 2; ++kk) {                                      \
                int u0 = kk * 8 + hi * 2;                                         \
                float4 a0 = *(const float4*)(lx + lo * 256                        \
                    + (((u0 & 8) | ((u0 & 7) ^ (lo & 7))) << 4));                 \
                float4 a1 = *(const float4*)(lx + lo * 256                        \
                    + ((((u0 + 1) & 8) | (((u0 + 1) & 7) ^ (lo & 7))) << 4));     \
                short8 af;                                                        \
                af[0] = f2bf(a0.x); af[1] = f2bf(a0.y);                           \
                af[2] = f2bf(a0.z); af[3] = f2bf(a0.w);                           \
                af[4] = f2bf(a1.x); af[5] = f2bf(a1.y);                           \
                af[6] = f2bf(a1.z); af[7] = f2bf(a1.w);                           \
                _Pragma("unroll")                                                 \
                for (int j = 0; j < 3; ++j)                                       \
                    acc[j] = __builtin_amdgcn_mfma_f32_16x16x32_bf16(             \
                        af, bfr[j][kk], acc[j], 0, 0, 0);                         \
            }                                                                     \
        }

    // Guarantee chunk t+1 landed before the barrier without blocking on the
    // newest prefetches (in-order retirement; steady in-flight <= 8).
    #define WAITQ(t)                                                              \
        {                                                                         \
            if ((t) <= 11)      asm volatile("s_waitcnt vmcnt(8)" ::: "memory");  \
            else if ((t) <= 13) asm volatile("s_waitcnt vmcnt(6)" ::: "memory");  \
            else                asm volatile("s_waitcnt vmcnt(0)" ::: "memory");  \
        }

    short8 bfrA[3][2], bfrB[3][2];

    LOADB(bfrA, 0);                               // 6 loads (oldest)
    __builtin_amdgcn_sched_barrier(0);
    STAGE(0, 0); STAGE(1, 1); STAGE(2, 2); STAGE(3, 3);   // +4
    __builtin_amdgcn_sched_barrier(0);
    asm volatile("s_waitcnt vmcnt(3)" ::: "memory");      // bfrA + chunk0 done
    __builtin_amdgcn_sched_barrier(0);
    __builtin_amdgcn_s_barrier();

    for (int tb = 0; tb < 8; ++tb) {
        int t0 = 2 * tb, t1 = 2 * tb + 1;
        LOADB(bfrB, t1);
        COMPUTE(bfrA, t0);
        if (t0 + 4 < QNC) STAGE((t0 + 4) % 5, t0 + 4);
        __builtin_amdgcn_sched_barrier(0);
        WAITQ(t0);
        __builtin_amdgcn_sched_barrier(0);
        __builtin_amdgcn_s_barrier();

        if (t1 + 1 < QNC) LOADB(bfrA, t1 + 1);
        COMPUTE(bfrB, t1);
        if (t1 + 4 < QNC) STAGE((t1 + 4) % 5, t1 + 4);
        if (t1 < QNC - 1) {
            __builtin_amdgcn_sched_barrier(0);
            WAITQ(t1);
            __builtin_amdgcn_sched_barrier(0);
            __builtin_amdgcn_s_barrier();
        }
    }
    #undef STAGE
    #undef LOADB
    #undef COMPUTE
    #undef WAITQ

    // ---- coalesced epilogue: bias in-register -> LDS tiles -> 16B stores ----
    __syncthreads();
    #pragma unroll
    for (int j = 0; j < 3; ++j) {
        int n = wn * 48 + j * 16 + lo;
        #pragma unroll
        for (int r = 0; r < 4; ++r) {
            int rr = 4 * hi + r;                      // local row 0..15
            float v = acc[j][r];
            if (n < 64) {
                *(unsigned short*)(eq + rr * 272 + n * 2) =
                    (unsigned short)f2bf(v + bq[n]);
            } else if (n < 128) {
                *(unsigned short*)(eq + rr * 272 + n * 2) =
                    (unsigned short)f2bf(v + bk[n - 64]);
            } else {
                ev[(n - 128) * 18 + rr] = (unsigned short)f2bf(v + bv[n - 128]);
            }
        }
    }
    __syncthreads();

    {
        // Q/K: 16 rows x 16 units (Q segs 0-7, K segs 8-15), 1 unit/thread
        int row = tid >> 4, seg = tid & 15;
        short8 val = *(const short8*)(eq + row * 272 + seg * 16);
        if (seg < 8)
            *(short8*)(Q + (size_t)(rowbase + row) * 64 + seg * 8) = val;
        else
            *(short8*)(K + (size_t)(rowbase + row) * 64 + (seg - 8) * 8) = val;
    }
    if (tid < 128) {
        // Vt: 64 h x 2 units (16 s each)
        int h = tid >> 1, su = tid & 1;
        int b = rowbase >> 11, sl0 = rowbase & (S_ - 1);
        short8 val = *(const short8*)((const char*)ev + h * 36 + su * 16);
        *(short8*)(Vt + ((size_t)(b * 64 + h)) * S_ + sl0 + su * 8) = val;
    }
}

// Flash attention, no-max softmax (unchanged from v10): 3-buffer LDS ring,
// depth-2 prefetch, one raw s_barrier per tile with counted vmcnt, masks
// pre-folded into a per-lane bitmask.
__global__ __launch_bounds__(256) void attn_stage(
    const unsigned short* __restrict__ Q, const unsigned short* __restrict__ K,
    const unsigned short* __restrict__ Vt, const int* __restrict__ mask,
    float* __restrict__ part)
{
    __shared__ __align__(16) char kv[3][16384];            // [K 8KB | V 8KB] x3
    __shared__ __align__(16) unsigned short p_lds[4][16][72];
    int tid = threadIdx.x;
    int wave = tid >> 6, lane = tid & 63;
    int lo = lane & 15, hi = lane >> 4;
    int blk = blockIdx.x;
    int c = blk & 3;
    int pr = blk >> 2;
    int b = pr & 7;
    int qt64 = 31 - (pr >> 3);          // heavy first
    int nkt = qt64 + 1;
    int chunk = (nkt + 3) >> 2;
    int kt0 = c * chunk;
    int kt1 = min(kt0 + chunk, nkt);
    int ntile = kt1 - kt0;              // <= 8
    int qrow0 = qt64 * 64 + wave * 16;

    f32x4 o[4];
    float ps[4] = {0.f, 0.f, 0.f, 0.f};
    #pragma unroll
    for (int i = 0; i < 4; ++i) o[i] = (f32x4){0.f, 0.f, 0.f, 0.f};

    #define ASTAGE(bb, kt)                                                        \
        {                                                                         \
            int kbase_ = (kt) * 64;                                               \
            const char* kg = (const char*)K + (size_t)(b * S_ + kbase_) * 128;    \
            const char* vg = (const char*)Vt + (size_t)b * 64 * 4096 + kbase_ * 2;\
            _Pragma("unroll")                                                     \
            for (int j = 0; j < 2; ++j) {                                         \
                int r = (j * 4 + wave) * 8 + (lane >> 3);                         \
                int un = lane & 7;                                                \
                g2l16(kg + r * 128 + ((un ^ (r & 7)) << 4),                       \
                      &kv[bb][(j * 4 + wave) * 1024]);                            \
                g2l16(vg + (size_t)r * 4096 + ((un ^ (r & 7)) << 4),              \
                      &kv[bb][8192 + (j * 4 + wave) * 1024]);                     \
            }                                                                     \
        }

    if (ntile > 0) {
        const unsigned short* qp = Q + ((size_t)(b * S_ + qrow0 + lo)) * 64 + 8 * hi;
        short8 qf0 = *(const short8*)(qp);
        short8 qf1 = *(const short8*)(qp + 32);

        unsigned mbits = 0;
        for (int tt = 0; tt < 8; ++tt) {
            if (tt < ntile) {
                int kbase = (kt0 + tt) * 64;
                #pragma unroll
                for (int nt = 0; nt < 4; ++nt)
                    if (mask[b * S_ + kbase + nt * 16 + lo] != 0)
                        mbits |= (1u << (tt * 4 + nt));
            }
        }
        asm volatile("s_waitcnt vmcnt(0)" ::: "memory");
        __builtin_amdgcn_sched_barrier(0);

        ASTAGE(0, kt0);
        if (ntile > 1) ASTAGE(1, kt0 + 1);
        __builtin_amdgcn_sched_barrier(0);
        if (ntile > 1) asm volatile("s_waitcnt vmcnt(4)" ::: "memory");
        else           asm volatile("s_waitcnt vmcnt(0)" ::: "memory");
        __builtin_amdgcn_sched_barrier(0);
        __builtin_amdgcn_s_barrier();

        for (int t = 0; t < ntile; ++t) {
            int kbase = (kt0 + t) * 64;
            const char* kb = kv[t % 3];
            const char* vb = kv[t % 3] + 8192;

            f32x4 s[4];
            #pragma unroll
            for (int i = 0; i < 4; ++i) s[i] = (f32x4){0.f, 0.f, 0.f, 0.f};
            #pragma unroll
            for (int nt = 0; nt < 4; ++nt) {
                short8 kf0 = *(const short8*)(kb + (nt * 16 + lo) * 128 + ((hi ^ (lo & 7)) << 4));
                short8 kf1 = *(const short8*)(kb + (nt * 16 + lo) * 128 + (((4 + hi) ^ (lo & 7)) << 4));
                s[nt] = __builtin_amdgcn_mfma_f32_16x16x32_bf16(qf0, kf0, s[nt], 0, 0, 0);
                s[nt] = __builtin_amdgcn_mfma_f32_16x16x32_bf16(qf1, kf1, s[nt], 0, 0, 0);
            }

            #pragma unroll
            for (int nt = 0; nt < 4; ++nt) {
                int kpos = kbase + nt * 16 + lo;
                bool mok = (mbits >> (t * 4 + nt)) & 1;
                #pragma unroll
                for (int r = 0; r < 4; ++r) {
                    int qpos = qrow0 + 4 * hi + r;
                    bool ok = mok && (kpos <= qpos);
                    float pv = ok ? __expf(s[nt][r] * 0.125f) : 0.f;
                    ps[r] += pv;
                    p_lds[wave][4 * hi + r][nt * 16 + lo] = (unsigned short)f2bf(pv);
                }
            }

            #pragma unroll
            for (int kk = 0; kk < 2; ++kk) {
                short8 pf = *(const short8*)&p_lds[wave][lo][kk * 32 + 8 * hi];
                #pragma unroll
                for (int nt = 0; nt < 4; ++nt) {
                    short8 vf = *(const short8*)(vb + (nt * 16 + lo) * 128
                                                 + (((kk * 4 + hi) ^ (lo & 7)) << 4));
                    o[nt] = __builtin_amdgcn_mfma_f32_16x16x32_bf16(pf, vf, o[nt], 0, 0, 0);
                }
            }

            if (t + 2 < ntile) ASTAGE((t + 2) % 3, kt0 + t + 2);
            __builtin_amdgcn_sched_barrier(0);
            if (t + 1 < ntile) {
                if (t + 2 < ntile) asm volatile("s_waitcnt vmcnt(4)" ::: "memory");
                else               asm volatile("s_waitcnt vmcnt(0)" ::: "memory");
                __builtin_amdgcn_sched_barrier(0);
                __builtin_amdgcn_s_barrier();
            }
        }
    }
    #undef ASTAGE

    float l[4];
    #pragma unroll
    for (int r = 0; r < 4; ++r) {
        float v = ps[r];
        v += __shfl_xor(v, 1);
        v += __shfl_xor(v, 2);
        v += __shfl_xor(v, 4);
        v += __shfl_xor(v, 8);
        l[r] = v;
    }

    int tile16 = b * 128 + qt64 * 4 + wave;
    float* pp = part + (((size_t)c * 1024 + tile16) * 64 + lane) * 20;
    #pragma unroll
    for (int nt = 0; nt < 4; ++nt) *(f32x4*)(pp + nt * 4) = o[nt];
    f32x4 ll;
    #pragma unroll
    for (int r = 0; r < 4; ++r) ll[r] = l[r];
    *(f32x4*)(pp + 16) = ll;
}

// Sum 4 kv-chunk partials (additive) and normalize.
__global__ __launch_bounds__(256) void attn_comb(
    const float* __restrict__ part, float* __restrict__ out)
{
    int g = blockIdx.x * 256 + threadIdx.x;   // 65536
    int tile = g >> 6, lane = g & 63;
    int lo = lane & 15, hi = lane >> 4;
    int b = tile >> 7, qt = tile & 127;
    int qrow0 = qt * 16;

    f32x4 o[4];
    float l[4] = {0.f, 0.f, 0.f, 0.f};
    #pragma unroll
    for (int i = 0; i < 4; ++i) o[i] = (f32x4){0.f, 0.f, 0.f, 0.f};

    #pragma unroll
    for (int c = 0; c < 4; ++c) {
        const float* pp = part + (((size_t)c * 1024 + tile) * 64 + lane) * 20;
        #pragma unroll
        for (int nt = 0; nt < 4; ++nt) {
            f32x4 po = *(const f32x4*)(pp + nt * 4);
            #pragma unroll
            for (int r = 0; r < 4; ++r) o[nt][r] += po[r];
        }
        f32x4 pl = *(const f32x4*)(pp + 16);
        #pragma unroll
        for (int r = 0; r < 4; ++r) l[r] += pl[r];
    }

    #pragma unroll
    for (int nt = 0; nt < 4; ++nt) {
        #pragma unroll
        for (int r = 0; r < 4; ++r) {
            int qpos = qrow0 + 4 * hi + r;
            out[((size_t)(b * S_ + qpos)) * 64 + nt * 16 + lo] =
                (l[r] > 0.f) ? o[nt][r] / l[r] : 0.f;
        }
    }
}

extern "C" void kernel_launch(void* const* d_in, const int* in_sizes, int n_in,
                              void* d_out, int out_size, void* d_ws, size_t ws_size,
                              hipStream_t stream) {
    const float* x   = (const float*)d_in[0];
    const int*   msk = (const int*)d_in[1];
    const float* Wq  = (const float*)d_in[2];
    const float* bq  = (const float*)d_in[3];
    const float* Wk  = (const float*)d_in[4];
    const float* bk  = (const float*)d_in[5];
    const float* Wv  = (const float*)d_in[6];
    const float* bv  = (const float*)d_in[7];
    float* outp = (float*)d_out;

    // ws layout: Wtt @0 (384KB, pad 512KB) | Q @0x080000 | K @0x280000
    //            Vt @0x480000 | part @0x680000 (4*1024*64*20 f32 = 21 MB)
    char* w = (char*)d_ws;
    unsigned short* Wtt = (unsigned short*)w;
    unsigned short* Qb = (unsigned short*)(w + 0x080000);
    unsigned short* Kb = (unsigned short*)(w + 0x280000);
    unsigned short* Vt = (unsigned short*)(w + 0x480000);
    float* partp = (float*)(w + 0x680000);

    prep_weights<<<dim3(96), dim3(256), 0, stream>>>(Wq, Wk, Wv, Wtt);
    qkv_main<<<dim3(1024), dim3(256), 0, stream>>>(x, Wtt, bq, bk, bv, Qb, Kb, Vt);
    attn_stage<<<dim3(1024), dim3(256), 0, stream>>>(Qb, Kb, Vt, msk, partp);
    attn_comb<<<dim3(256), dim3(256), 0, stream>>>(partp, outp);
}

// Round 12
// 58.319 us; speedup vs baseline: 1.0484x; 1.0484x over previous
//
#include <hip/hip_runtime.h>
#include <hip/hip_bf16.h>

#define S_ 2048
#define E_ 1024
#define QNC 16   // qkv K-chunks of 64 f32

typedef __attribute__((ext_vector_type(8))) short short8;
typedef __attribute__((ext_vector_type(4))) float f32x4;

__device__ __forceinline__ short f2bf(float f) {
    __hip_bfloat16 h = __float2bfloat16(f);
    return *(short*)&h;
}

__device__ __forceinline__ void g2l16(const void* g, void* l) {
    __builtin_amdgcn_global_load_lds(
        (const __attribute__((address_space(1))) void*)g,
        (__attribute__((address_space(3))) void*)l, 16, 0, 0);
}

// Wq/Wk/Wv [1024][64] f32 -> Wt bf16 [192 cols][1024 K] (col-major per output).
__global__ __launch_bounds__(256) void prep_weights(
    const float* __restrict__ Wq, const float* __restrict__ Wk,
    const float* __restrict__ Wv, unsigned short* __restrict__ Wt)
{
    int idx = blockIdx.x * 256 + threadIdx.x;  // 192*1024, grid 768
    int n = idx >> 10, k = idx & (E_ - 1);
    const float* W = (n < 64) ? Wq : (n < 128) ? Wk : Wv;
    Wt[idx] = (unsigned short)f2bf(W[k * 64 + (n & 63)]);
}

// QKV v12 — attn_stage-pattern clone: BOTH operands DMA-staged, zero global
// register loads in the loop. M=32/block, 512 blocks x 256 thr (4 waves:
// wm = 16-row half, wn = 96-col half). K-chunk 64 f32: x 8KB + Wt 24KB per
// buffer, 2-buffer ring (64KB -> 2 blocks/CU). Issue-early staging, vmcnt(0)
// + s_barrier per chunk (queue holds only the next chunk at the wait).
// 16B-unit XOR swizzle both sides -> conflict-free ds_read_b128.
__global__ __launch_bounds__(256, 2) void qkv_main(
    const float* __restrict__ x, const unsigned short* __restrict__ Wt,
    const float* __restrict__ bq, const float* __restrict__ bk,
    const float* __restrict__ bv,
    unsigned short* __restrict__ Q, unsigned short* __restrict__ K,
    unsigned short* __restrict__ Vt)
{
    __shared__ __align__(16) char pool[2][32768];   // [x 8KB | Wt 24KB] x2
    int tid = threadIdx.x;
    int wave = tid >> 6, lane = tid & 63;
    int lo = lane & 15, hi = lane >> 4;
    int wm = wave >> 1, wn = wave & 1;
    int rowbase = blockIdx.x * 32;
    const char* xg = (const char*)x;
    const char* wg = (const char*)Wt;

    f32x4 acc[6];
    #pragma unroll
    for (int j = 0; j < 6; ++j) acc[j] = (f32x4){0.f, 0.f, 0.f, 0.f};

    // chunk kc: x = 32 rows x 256B (512 units), Wt = 192 cols x 128B (1536
    // units). 8 DMA/thread, wave-uniform dst + lane*16, pre-swizzled source.
    #define STAGE(bb, kc)                                                         \
        {                                                                         \
            _Pragma("unroll")                                                     \
            for (int i = 0; i < 2; ++i) {                                         \
                int u_lin = i * 256 + tid;                                        \
                int r = u_lin >> 4, u = u_lin & 15;                               \
                const char* src = xg + (size_t)(rowbase + r) * 4096 + (kc) * 256  \
                                  + (((u & 8) | ((u & 7) ^ (r & 7))) << 4);       \
                g2l16(src, &pool[bb][(i * 256 + wave * 64) * 16]);                \
            }                                                                     \
            _Pragma("unroll")                                                     \
            for (int i = 0; i < 6; ++i) {                                         \
                int u_lin = i * 256 + tid;                                        \
                int c = u_lin >> 3, u = u_lin & 7;                                \
                const char* src = wg + (size_t)c * 2048 + (kc) * 128              \
                                  + ((u ^ (c & 7)) << 4);                         \
                g2l16(src, &pool[bb][8192 + (i * 256 + wave * 64) * 16]);         \
            }                                                                     \
        }

    STAGE(0, 0);
    asm volatile("s_waitcnt vmcnt(0)" ::: "memory");
    __builtin_amdgcn_sched_barrier(0);
    __builtin_amdgcn_s_barrier();

    for (int t = 0; t < QNC; ++t) {
        if (t + 1 < QNC) STAGE((t + 1) & 1, t + 1);   // issue-early

        const char* lx = pool[t & 1];
        const char* lw = pool[t & 1] + 8192;
        int r = wm * 16 + lo;
        #pragma unroll
        for (int kk = 0; kk < 2; ++kk) {
            int u0 = kk * 8 + hi * 2;
            float4 a0 = *(const float4*)(lx + r * 256
                + (((u0 & 8) | ((u0 & 7) ^ (r & 7))) << 4));
            float4 a1 = *(const float4*)(lx + r * 256
                + ((((u0 + 1) & 8) | (((u0 + 1) & 7) ^ (r & 7))) << 4));
            short8 af;
            af[0] = f2bf(a0.x); af[1] = f2bf(a0.y);
            af[2] = f2bf(a0.z); af[3] = f2bf(a0.w);
            af[4] = f2bf(a1.x); af[5] = f2bf(a1.y);
            af[6] = f2bf(a1.z); af[7] = f2bf(a1.w);
            #pragma unroll
            for (int j = 0; j < 6; ++j) {
                int c = wn * 96 + j * 16 + lo;
                short8 bf = *(const short8*)(lw + c * 128
                    + (((kk * 4 + hi) ^ (c & 7)) << 4));
                acc[j] = __builtin_amdgcn_mfma_f32_16x16x32_bf16(af, bf, acc[j], 0, 0, 0);
            }
        }

        __builtin_amdgcn_sched_barrier(0);
        asm volatile("s_waitcnt vmcnt(0)" ::: "memory");   // next chunk landed
        __builtin_amdgcn_sched_barrier(0);
        __builtin_amdgcn_s_barrier();
    }
    #undef STAGE

    // ---- coalesced epilogue: bias -> LDS tiles (alias ring) -> 16B stores ----
    char* eq = pool[0];                          // [32 rows][272B] = 8704B
    unsigned short* ev = (unsigned short*)pool[1];  // [64 h][40 shorts] = 5120B
    #pragma unroll
    for (int j = 0; j < 6; ++j) {
        int n = wn * 96 + j * 16 + lo;
        #pragma unroll
        for (int rr4 = 0; rr4 < 4; ++rr4) {
            int rr = wm * 16 + 4 * hi + rr4;           // local row 0..31
            float v = acc[j][rr4];
            if (n < 64) {
                *(unsigned short*)(eq + rr * 272 + n * 2) =
                    (unsigned short)f2bf(v + bq[n]);
            } else if (n < 128) {
                *(unsigned short*)(eq + rr * 272 + n * 2) =
                    (unsigned short)f2bf(v + bk[n - 64]);
            } else {
                ev[(n - 128) * 40 + rr] = (unsigned short)f2bf(v + bv[n - 128]);
            }
        }
    }
    __syncthreads();

    {
        // Q/K: 32 rows x 16 units (Q 0-7, K 8-15), 2 units/thread
        #pragma unroll
        for (int i = 0; i < 2; ++i) {
            int u_lin = i * 256 + tid;
            int row = u_lin >> 4, seg = u_lin & 15;
            short8 val = *(const short8*)(eq + row * 272 + seg * 16);
            if (seg < 8)
                *(short8*)(Q + (size_t)(rowbase + row) * 64 + seg * 8) = val;
            else
                *(short8*)(K + (size_t)(rowbase + row) * 64 + (seg - 8) * 8) = val;
        }
        // Vt: 64 h x 4 units (8 s each), 1 unit/thread
        int h = tid >> 2, su = tid & 3;
        int b = rowbase >> 11, sl0 = rowbase & (S_ - 1);
        short8 val = *(const short8*)(ev + h * 40 + su * 8);
        *(short8*)(Vt + ((size_t)(b * 64 + h)) * S_ + sl0 + su * 8) = val;
    }
}

// Flash attention, no-max softmax (unchanged): 3-buffer LDS ring, depth-2
// prefetch, one raw s_barrier per tile with counted vmcnt, masks pre-folded.
__global__ __launch_bounds__(256) void attn_stage(
    const unsigned short* __restrict__ Q, const unsigned short* __restrict__ K,
    const unsigned short* __restrict__ Vt, const int* __restrict__ mask,
    float* __restrict__ part)
{
    __shared__ __align__(16) char kv[3][16384];            // [K 8KB | V 8KB] x3
    __shared__ __align__(16) unsigned short p_lds[4][16][72];
    int tid = threadIdx.x;
    int wave = tid >> 6, lane = tid & 63;
    int lo = lane & 15, hi = lane >> 4;
    int blk = blockIdx.x;
    int c = blk & 3;
    int pr = blk >> 2;
    int b = pr & 7;
    int qt64 = 31 - (pr >> 3);          // heavy first
    int nkt = qt64 + 1;
    int chunk = (nkt + 3) >> 2;
    int kt0 = c * chunk;
    int kt1 = min(kt0 + chunk, nkt);
    int ntile = kt1 - kt0;              // <= 8
    int qrow0 = qt64 * 64 + wave * 16;

    f32x4 o[4];
    float ps[4] = {0.f, 0.f, 0.f, 0.f};
    #pragma unroll
    for (int i = 0; i < 4; ++i) o[i] = (f32x4){0.f, 0.f, 0.f, 0.f};

    #define ASTAGE(bb, kt)                                                        \
        {                                                                         \
            int kbase_ = (kt) * 64;                                               \
            const char* kg = (const char*)K + (size_t)(b * S_ + kbase_) * 128;    \
            const char* vg = (const char*)Vt + (size_t)b * 64 * 4096 + kbase_ * 2;\
            _Pragma("unroll")                                                     \
            for (int j = 0; j < 2; ++j) {                                         \
                int r = (j * 4 + wave) * 8 + (lane >> 3);                         \
                int un = lane & 7;                                                \
                g2l16(kg + r * 128 + ((un ^ (r & 7)) << 4),                       \
                      &kv[bb][(j * 4 + wave) * 1024]);                            \
                g2l16(vg + (size_t)r * 4096 + ((un ^ (r & 7)) << 4),              \
                      &kv[bb][8192 + (j * 4 + wave) * 1024]);                     \
            }                                                                     \
        }

    if (ntile > 0) {
        const unsigned short* qp = Q + ((size_t)(b * S_ + qrow0 + lo)) * 64 + 8 * hi;
        short8 qf0 = *(const short8*)(qp);
        short8 qf1 = *(const short8*)(qp + 32);

        unsigned mbits = 0;
        for (int tt = 0; tt < 8; ++tt) {
            if (tt < ntile) {
                int kbase = (kt0 + tt) * 64;
                #pragma unroll
                for (int nt = 0; nt < 4; ++nt)
                    if (mask[b * S_ + kbase + nt * 16 + lo] != 0)
                        mbits |= (1u << (tt * 4 + nt));
            }
        }
        asm volatile("s_waitcnt vmcnt(0)" ::: "memory");
        __builtin_amdgcn_sched_barrier(0);

        ASTAGE(0, kt0);
        if (ntile > 1) ASTAGE(1, kt0 + 1);
        __builtin_amdgcn_sched_barrier(0);
        if (ntile > 1) asm volatile("s_waitcnt vmcnt(4)" ::: "memory");
        else           asm volatile("s_waitcnt vmcnt(0)" ::: "memory");
        __builtin_amdgcn_sched_barrier(0);
        __builtin_amdgcn_s_barrier();

        for (int t = 0; t < ntile; ++t) {
            int kbase = (kt0 + t) * 64;
            const char* kb = kv[t % 3];
            const char* vb = kv[t % 3] + 8192;

            f32x4 s[4];
            #pragma unroll
            for (int i = 0; i < 4; ++i) s[i] = (f32x4){0.f, 0.f, 0.f, 0.f};
            #pragma unroll
            for (int nt = 0; nt < 4; ++nt) {
                short8 kf0 = *(const short8*)(kb + (nt * 16 + lo) * 128 + ((hi ^ (lo & 7)) << 4));
                short8 kf1 = *(const short8*)(kb + (nt * 16 + lo) * 128 + (((4 + hi) ^ (lo & 7)) << 4));
                s[nt] = __builtin_amdgcn_mfma_f32_16x16x32_bf16(qf0, kf0, s[nt], 0, 0, 0);
                s[nt] = __builtin_amdgcn_mfma_f32_16x16x32_bf16(qf1, kf1, s[nt], 0, 0, 0);
            }

            #pragma unroll
            for (int nt = 0; nt < 4; ++nt) {
                int kpos = kbase + nt * 16 + lo;
                bool mok = (mbits >> (t * 4 + nt)) & 1;
                #pragma unroll
                for (int r = 0; r < 4; ++r) {
                    int qpos = qrow0 + 4 * hi + r;
                    bool ok = mok && (kpos <= qpos);
                    float pv = ok ? __expf(s[nt][r] * 0.125f) : 0.f;
                    ps[r] += pv;
                    p_lds[wave][4 * hi + r][nt * 16 + lo] = (unsigned short)f2bf(pv);
                }
            }

            #pragma unroll
            for (int kk = 0; kk < 2; ++kk) {
                short8 pf = *(const short8*)&p_lds[wave][lo][kk * 32 + 8 * hi];
                #pragma unroll
                for (int nt = 0; nt < 4; ++nt) {
                    short8 vf = *(const short8*)(vb + (nt * 16 + lo) * 128
                                                 + (((kk * 4 + hi) ^ (lo & 7)) << 4));
                    o[nt] = __builtin_amdgcn_mfma_f32_16x16x32_bf16(pf, vf, o[nt], 0, 0, 0);
                }
            }

            if (t + 2 < ntile) ASTAGE((t + 2) % 3, kt0 + t + 2);
            __builtin_amdgcn_sched_barrier(0);
            if (t + 1 < ntile) {
                if (t + 2 < ntile) asm volatile("s_waitcnt vmcnt(4)" ::: "memory");
                else               asm volatile("s_waitcnt vmcnt(0)" ::: "memory");
                __builtin_amdgcn_sched_barrier(0);
                __builtin_amdgcn_s_barrier();
            }
        }
    }
    #undef ASTAGE

    float l[4];
    #pragma unroll
    for (int r = 0; r < 4; ++r) {
        float v = ps[r];
        v += __shfl_xor(v, 1);
        v += __shfl_xor(v, 2);
        v += __shfl_xor(v, 4);
        v += __shfl_xor(v, 8);
        l[r] = v;
    }

    int tile16 = b * 128 + qt64 * 4 + wave;
    float* pp = part + (((size_t)c * 1024 + tile16) * 64 + lane) * 20;
    #pragma unroll
    for (int nt = 0; nt < 4; ++nt) *(f32x4*)(pp + nt * 4) = o[nt];
    f32x4 ll;
    #pragma unroll
    for (int r = 0; r < 4; ++r) ll[r] = l[r];
    *(f32x4*)(pp + 16) = ll;
}

// Sum 4 kv-chunk partials (additive) and normalize.
__global__ __launch_bounds__(256) void attn_comb(
    const float* __restrict__ part, float* __restrict__ out)
{
    int g = blockIdx.x * 256 + threadIdx.x;   // 65536
    int tile = g >> 6, lane = g & 63;
    int lo = lane & 15, hi = lane >> 4;
    int b = tile >> 7, qt = tile & 127;
    int qrow0 = qt * 16;

    f32x4 o[4];
    float l[4] = {0.f, 0.f, 0.f, 0.f};
    #pragma unroll
    for (int i = 0; i < 4; ++i) o[i] = (f32x4){0.f, 0.f, 0.f, 0.f};

    #pragma unroll
    for (int c = 0; c < 4; ++c) {
        const float* pp = part + (((size_t)c * 1024 + tile) * 64 + lane) * 20;
        #pragma unroll
        for (int nt = 0; nt < 4; ++nt) {
            f32x4 po = *(const f32x4*)(pp + nt * 4);
            #pragma unroll
            for (int r = 0; r < 4; ++r) o[nt][r] += po[r];
        }
        f32x4 pl = *(const f32x4*)(pp + 16);
        #pragma unroll
        for (int r = 0; r < 4; ++r) l[r] += pl[r];
    }

    #pragma unroll
    for (int nt = 0; nt < 4; ++nt) {
        #pragma unroll
        for (int r = 0; r < 4; ++r) {
            int qpos = qrow0 + 4 * hi + r;
            out[((size_t)(b * S_ + qpos)) * 64 + nt * 16 + lo] =
                (l[r] > 0.f) ? o[nt][r] / l[r] : 0.f;
        }
    }
}

extern "C" void kernel_launch(void* const* d_in, const int* in_sizes, int n_in,
                              void* d_out, int out_size, void* d_ws, size_t ws_size,
                              hipStream_t stream) {
    const float* x   = (const float*)d_in[0];
    const int*   msk = (const int*)d_in[1];
    const float* Wq  = (const float*)d_in[2];
    const float* bq  = (const float*)d_in[3];
    const float* Wk  = (const float*)d_in[4];
    const float* bk  = (const float*)d_in[5];
    const float* Wv  = (const float*)d_in[6];
    const float* bv  = (const float*)d_in[7];
    float* outp = (float*)d_out;

    // ws layout: Wt @0 (384KB, pad 512KB) | Q @0x080000 | K @0x280000
    //            Vt @0x480000 | part @0x680000 (4*1024*64*20 f32 = 21 MB)
    char* w = (char*)d_ws;
    unsigned short* Wt = (unsigned short*)w;
    unsigned short* Qb = (unsigned short*)(w + 0x080000);
    unsigned short* Kb = (unsigned short*)(w + 0x280000);
    unsigned short* Vt = (unsigned short*)(w + 0x480000);
    float* partp = (float*)(w + 0x680000);

    prep_weights<<<dim3(768), dim3(256), 0, stream>>>(Wq, Wk, Wv, Wt);
    qkv_main<<<dim3(512), dim3(256), 0, stream>>>(x, Wt, bq, bk, bv, Qb, Kb, Vt);
    attn_stage<<<dim3(1024), dim3(256), 0, stream>>>(Qb, Kb, Vt, msk, partp);
    attn_comb<<<dim3(256), dim3(256), 0, stream>>>(partp, outp);
}